// Round 1
// baseline (772.258 us; speedup 1.0000x reference)
//
#include <hip/hip_runtime.h>

// ROIBBoxHead: out = relu(relu(X@W1+b1)@W2+b2)@W3+b3
// X=[4096,12544] fp32, W1=[12544,1024], W2=[1024,1024], W3=[1024,324].
// Strategy: split-bf16 emulated-fp32 GEMM on the MFMA pipe:
//   a*b ~= ah*bh + ah*bl + al*bh   (error ~2^-16 relative)
// 128x128 tile, BK=64, 4 waves, mfma_f32_16x16x32_bf16, XOR-swizzled LDS.

typedef __attribute__((ext_vector_type(4)))  float          f32x4;
typedef __attribute__((ext_vector_type(8)))  short          short8;
typedef __attribute__((ext_vector_type(4)))  unsigned int   uint4v;
typedef __attribute__((ext_vector_type(4)))  unsigned short ushort4v;

#define BM 128
#define BN 128
#define BK 64

// Truncation split: x ~= hi + lo, |x - hi - lo| <= 2^-16 |x|.
// (Rounding mode of hi is irrelevant: lo captures the residual.)
__device__ __forceinline__ void split_f32(float x, unsigned short& h, unsigned short& l) {
    unsigned int u = __float_as_uint(x);
    h = (unsigned short)(u >> 16);
    float hf = __uint_as_float(u & 0xFFFF0000u);
    l = (unsigned short)(__float_as_uint(x - hf) >> 16);
}

// ---------------------------------------------------------------------------
// Weight conversion: W[K][N] fp32 -> WhT[Npad][K], WlT[Npad][K] bf16 planes
// (transposed so the MFMA B-fragment reads 8 consecutive k as one b128).
// Rows n in [N, Npad) are zero-filled. grid = (Npad/32, K/32), block = (32,8).
// ---------------------------------------------------------------------------
__global__ void convert_w_t(const float* __restrict__ W,
                            unsigned short* __restrict__ WhT,
                            unsigned short* __restrict__ WlT,
                            int K, int N) {
    __shared__ float tile[32][33];
    const int k0 = blockIdx.y * 32;
    const int n0 = blockIdx.x * 32;
    const int tx = threadIdx.x;   // 0..31
    const int ty = threadIdx.y;   // 0..7
#pragma unroll
    for (int i = 0; i < 4; ++i) {
        const int r = ty + 8 * i;         // local k
        const int n = n0 + tx;
        tile[r][tx] = (n < N) ? W[(size_t)(k0 + r) * N + n] : 0.0f;
    }
    __syncthreads();
#pragma unroll
    for (int i = 0; i < 4; ++i) {
        const int r = ty + 8 * i;         // local n
        const float v = tile[tx][r];      // = W[k0+tx][n0+r]
        unsigned short h, l;
        split_f32(v, h, l);
        const size_t o = (size_t)(n0 + r) * K + k0 + tx;
        WhT[o] = h;
        WlT[o] = l;
    }
}

// ---------------------------------------------------------------------------
// Split-bf16 GEMM: C[M,N] = A[M,K] @ B[K,N] (+bias, optional relu)
//   A_F32:      A comes from fp32 (converted to hi/lo during staging)
//   RELU_SPLIT: epilogue = relu(+bias), write bf16 hi/lo planes (ldC=1024)
//   else:       epilogue = +bias, write fp32 with gn<N_out bound (GEMM3)
// grid = (M/BM, Ntiles) -> M-major so XCD round-robin gives M-stripes.
// ---------------------------------------------------------------------------
template<bool A_F32, bool RELU_SPLIT>
__global__ __launch_bounds__(256, 2)
void gemm3split(const float* __restrict__ A32,
                const unsigned short* __restrict__ Ah,
                const unsigned short* __restrict__ Al,
                const unsigned short* __restrict__ BhT,
                const unsigned short* __restrict__ BlT,
                const float* __restrict__ bias,
                unsigned short* __restrict__ Ch,
                unsigned short* __restrict__ Cl,
                float* __restrict__ Cf,
                int K, int N_out) {
    const int tid  = threadIdx.x;
    const int lane = tid & 63;
    const int wave = tid >> 6;
    const int kgrp = lane >> 4;
    const int m0 = blockIdx.x * BM;          // M-major grid
    const int n0 = blockIdx.y * BN;
    const int wm = (wave >> 1) * 64;
    const int wn = (wave & 1) * 64;

    __shared__ __align__(16) unsigned short sAh[BM * BK];
    __shared__ __align__(16) unsigned short sAl[BM * BK];
    __shared__ __align__(16) unsigned short sBh[BN * BK];
    __shared__ __align__(16) unsigned short sBl[BN * BK];

    f32x4 acc[4][4];
#pragma unroll
    for (int m = 0; m < 4; ++m)
#pragma unroll
        for (int n = 0; n < 4; ++n) acc[m][n] = (f32x4){0.f, 0.f, 0.f, 0.f};

    const int arow   = tid >> 4;   // A_F32 staging: 16 rows x 16 chunks(4 floats)
    const int acol4  = tid & 15;
    const int brow   = tid >> 3;   // bf16 staging: 32 rows x 8 chunks(8 bf16)
    const int bchunk = tid & 7;

    f32x4  aF[8];
    uint4v aH[4], aL[4];
    uint4v bH[4], bL[4];

    const int nkt = K / BK;

    auto load_tile = [&](int kt) {
        const int k0 = kt * BK;
        if constexpr (A_F32) {
#pragma unroll
            for (int i = 0; i < 8; ++i)
                aF[i] = *(const f32x4*)(A32 + (size_t)(m0 + arow + 16 * i) * K + k0 + acol4 * 4);
        } else {
#pragma unroll
            for (int i = 0; i < 4; ++i) {
                const size_t off = (size_t)(m0 + brow + 32 * i) * K + k0 + bchunk * 8;
                aH[i] = *(const uint4v*)(Ah + off);
                aL[i] = *(const uint4v*)(Al + off);
            }
        }
#pragma unroll
        for (int i = 0; i < 4; ++i) {
            const size_t off = (size_t)(n0 + brow + 32 * i) * K + k0 + bchunk * 8;
            bH[i] = *(const uint4v*)(BhT + off);
            bL[i] = *(const uint4v*)(BlT + off);
        }
    };

    auto stage_to_lds = [&]() {
        if constexpr (A_F32) {
#pragma unroll
            for (int i = 0; i < 8; ++i) {
                const int r = arow + 16 * i;
                ushort4v h, l;
#pragma unroll
                for (int j = 0; j < 4; ++j) {
                    unsigned short hh, ll;
                    split_f32(aF[i][j], hh, ll);
                    h[j] = hh; l[j] = ll;
                }
                const int ck  = acol4 >> 1;
                const int sub = (acol4 & 1) * 4;
                const int off = r * BK + ((ck ^ (r & 7)) << 3) + sub;
                *(ushort4v*)(sAh + off) = h;
                *(ushort4v*)(sAl + off) = l;
            }
        } else {
#pragma unroll
            for (int i = 0; i < 4; ++i) {
                const int r   = brow + 32 * i;
                const int off = r * BK + ((bchunk ^ (r & 7)) << 3);
                *(uint4v*)(sAh + off) = aH[i];
                *(uint4v*)(sAl + off) = aL[i];
            }
        }
#pragma unroll
        for (int i = 0; i < 4; ++i) {
            const int r   = brow + 32 * i;
            const int off = r * BK + ((bchunk ^ (r & 7)) << 3);
            *(uint4v*)(sBh + off) = bH[i];
            *(uint4v*)(sBl + off) = bL[i];
        }
    };

    load_tile(0);

    for (int kt = 0; kt < nkt; ++kt) {
        __syncthreads();                 // prev compute done; prologue loads drained
        stage_to_lds();
        __syncthreads();                 // LDS ready
        if (kt + 1 < nkt) load_tile(kt + 1);   // issued AFTER barrier -> vmcnt drain
                                               // lands at NEXT iter's barrier (hidden)
#pragma unroll
        for (int kk = 0; kk < BK / 32; ++kk) {
            const int ck = kk * 4 + kgrp;
            short8 fah[4], fal[4];
#pragma unroll
            for (int m = 0; m < 4; ++m) {
                const int r   = wm + m * 16 + (lane & 15);
                const int off = r * BK + ((ck ^ (r & 7)) << 3);
                fah[m] = *(const short8*)(sAh + off);
                fal[m] = *(const short8*)(sAl + off);
            }
#pragma unroll
            for (int n = 0; n < 4; ++n) {
                const int r   = wn + n * 16 + (lane & 15);
                const int off = r * BK + ((ck ^ (r & 7)) << 3);
                const short8 fbh = *(const short8*)(sBh + off);
                const short8 fbl = *(const short8*)(sBl + off);
#pragma unroll
                for (int m = 0; m < 4; ++m) {
                    acc[m][n] = __builtin_amdgcn_mfma_f32_16x16x32_bf16(fah[m], fbh, acc[m][n], 0, 0, 0);
                    acc[m][n] = __builtin_amdgcn_mfma_f32_16x16x32_bf16(fah[m], fbl, acc[m][n], 0, 0, 0);
                    acc[m][n] = __builtin_amdgcn_mfma_f32_16x16x32_bf16(fal[m], fbh, acc[m][n], 0, 0, 0);
                }
            }
        }
    }

    // Epilogue. C/D layout (verified): col = lane&15, row = (lane>>4)*4 + reg.
    const int col  = lane & 15;
    const int row4 = (lane >> 4) * 4;
#pragma unroll
    for (int n = 0; n < 4; ++n) {
        const int gn = n0 + wn + n * 16 + col;
        if constexpr (RELU_SPLIT) {
            const float bv = bias[gn];
#pragma unroll
            for (int m = 0; m < 4; ++m) {
                const int gmb = m0 + wm + m * 16 + row4;
#pragma unroll
                for (int j = 0; j < 4; ++j) {
                    float v = acc[m][n][j] + bv;
                    v = fmaxf(v, 0.0f);
                    unsigned short hh, ll;
                    split_f32(v, hh, ll);
                    const size_t o = (size_t)(gmb + j) * 1024 + gn;
                    Ch[o] = hh;
                    Cl[o] = ll;
                }
            }
        } else {
            if (gn < N_out) {
                const float bv = bias[gn];
#pragma unroll
                for (int m = 0; m < 4; ++m) {
                    const int gmb = m0 + wm + m * 16 + row4;
#pragma unroll
                    for (int j = 0; j < 4; ++j) {
                        Cf[(size_t)(gmb + j) * N_out + gn] = acc[m][n][j] + bv;
                    }
                }
            }
        }
    }
}

// ---------------------------------------------------------------------------
// Workspace layout (bytes). Total = 90,701,824 (~86.5 MB).
// ---------------------------------------------------------------------------
static constexpr size_t SZ_W1P  = (size_t)1024 * 12544 * 2;   // 25,690,112
static constexpr size_t SZ_W2P  = (size_t)1024 * 1024  * 2;   //  2,097,152
static constexpr size_t SZ_W3P  = (size_t)384  * 1024  * 2;   //    786,432
static constexpr size_t SZ_CP   = (size_t)4096 * 1024  * 2;   //  8,388,608
static constexpr size_t OFF_W1H = 0;
static constexpr size_t OFF_W1L = OFF_W1H + SZ_W1P;
static constexpr size_t OFF_W2H = OFF_W1L + SZ_W1P;
static constexpr size_t OFF_W2L = OFF_W2H + SZ_W2P;
static constexpr size_t OFF_W3H = OFF_W2L + SZ_W2P;
static constexpr size_t OFF_W3L = OFF_W3H + SZ_W3P;
static constexpr size_t OFF_C1H = OFF_W3L + SZ_W3P;
static constexpr size_t OFF_C1L = OFF_C1H + SZ_CP;
static constexpr size_t OFF_C2H = OFF_C1L + SZ_CP;
static constexpr size_t OFF_C2L = OFF_C2H + SZ_CP;
static constexpr size_t WS_NEED = OFF_C2L + SZ_CP;

extern "C" void kernel_launch(void* const* d_in, const int* in_sizes, int n_in,
                              void* d_out, int out_size, void* d_ws, size_t ws_size,
                              hipStream_t stream) {
    const float* features = (const float*)d_in[0];
    // d_in[1] = batch_indices: mathematically dead (permutation cancels).
    const float* w1 = (const float*)d_in[2];
    const float* b1 = (const float*)d_in[3];
    const float* w2 = (const float*)d_in[4];
    const float* b2 = (const float*)d_in[5];
    const float* w3 = (const float*)d_in[6];
    const float* b3 = (const float*)d_in[7];
    float* out = (float*)d_out;

    if (ws_size < WS_NEED) return;   // visible failure rather than corruption

    char* ws = (char*)d_ws;
    unsigned short* W1h = (unsigned short*)(ws + OFF_W1H);
    unsigned short* W1l = (unsigned short*)(ws + OFF_W1L);
    unsigned short* W2h = (unsigned short*)(ws + OFF_W2H);
    unsigned short* W2l = (unsigned short*)(ws + OFF_W2L);
    unsigned short* W3h = (unsigned short*)(ws + OFF_W3H);
    unsigned short* W3l = (unsigned short*)(ws + OFF_W3L);
    unsigned short* C1h = (unsigned short*)(ws + OFF_C1H);
    unsigned short* C1l = (unsigned short*)(ws + OFF_C1L);
    unsigned short* C2h = (unsigned short*)(ws + OFF_C2H);
    unsigned short* C2l = (unsigned short*)(ws + OFF_C2L);

    const dim3 cblk(32, 8);
    convert_w_t<<<dim3(1024 / 32, 12544 / 32), cblk, 0, stream>>>(w1, W1h, W1l, 12544, 1024);
    convert_w_t<<<dim3(1024 / 32, 1024  / 32), cblk, 0, stream>>>(w2, W2h, W2l, 1024, 1024);
    convert_w_t<<<dim3(384  / 32, 1024  / 32), cblk, 0, stream>>>(w3, W3h, W3l, 1024, 324);

    // L1: [4096,12544] @ [12544,1024] -> relu -> split planes
    gemm3split<true, true><<<dim3(4096 / BM, 1024 / BN), 256, 0, stream>>>(
        features, nullptr, nullptr, W1h, W1l, b1, C1h, C1l, nullptr, 12544, 1024);
    // L2: [4096,1024] @ [1024,1024] -> relu -> split planes
    gemm3split<false, true><<<dim3(4096 / BM, 1024 / BN), 256, 0, stream>>>(
        nullptr, C1h, C1l, W2h, W2l, b2, C2h, C2l, nullptr, 1024, 1024);
    // L3: [4096,1024] @ [1024,324] -> fp32 out (N padded to 384 in W3 planes)
    gemm3split<false, false><<<dim3(4096 / BM, 384 / BN), 256, 0, stream>>>(
        nullptr, C2h, C2l, W3h, W3l, b3, nullptr, nullptr, out, 1024, 324);
}

// Round 2
// 635.191 us; speedup vs baseline: 1.2158x; 1.2158x over previous
//
#include <hip/hip_runtime.h>

// ROIBBoxHead: out = relu(relu(X@W1+b1)@W2+b2)@W3+b3
// X=[4096,12544] fp32, W1=[12544,1024], W2=[1024,1024], W3=[1024,324].
// Split-bf16 emulated-fp32 GEMM on the MFMA pipe:
//   a*b ~= ah*bh + ah*bl + al*bh   (error ~2^-16 relative)
// 128x128 tile, BK=64, 4 waves, mfma_f32_16x16x32_bf16, XOR-swizzled LDS.
// R2: split-K (GEMM1 z=2, GEMM3 z=4) -> 2 resident blocks/CU; vectorized
// transpose-converts; fused reduce(+bias+relu+split) epilogue kernels.

typedef __attribute__((ext_vector_type(4)))  float          f32x4;
typedef __attribute__((ext_vector_type(8)))  short          short8;
typedef __attribute__((ext_vector_type(4)))  unsigned int   uint4v;
typedef __attribute__((ext_vector_type(4)))  unsigned short ushort4v;
typedef __attribute__((ext_vector_type(8)))  unsigned short ushort8v;

#define BM 128
#define BN 128
#define BK 64

// Truncation split: x ~= hi + lo, |x - hi - lo| <= 2^-16 |x|.
__device__ __forceinline__ void split_f32(float x, unsigned short& h, unsigned short& l) {
    unsigned int u = __float_as_uint(x);
    h = (unsigned short)(u >> 16);
    float hf = __uint_as_float(u & 0xFFFF0000u);
    l = (unsigned short)(__float_as_uint(x - hf) >> 16);
}

// ---------------------------------------------------------------------------
// Weight conversion: W[K][N] fp32 -> WhT[Npad][K], WlT[Npad][K] bf16 planes.
// 64x64 LDS transpose tile; vectorized ushort8 stores along K.
// grid = (Npad/64, K/64), block = 256.
// ---------------------------------------------------------------------------
__global__ __launch_bounds__(256) void convert_w_t(const float* __restrict__ W,
                                                   unsigned short* __restrict__ WhT,
                                                   unsigned short* __restrict__ WlT,
                                                   int K, int N) {
    __shared__ float tile[64][65];
    const int k0 = blockIdx.y * 64;
    const int n0 = blockIdx.x * 64;
    const int tid = threadIdx.x;
    const int kr = tid >> 4;          // 0..15
    const int nc = (tid & 15) * 4;    // 0..60
#pragma unroll
    for (int i = 0; i < 4; ++i) {
        const int k = kr + 16 * i;
        f32x4 v = (f32x4){0.f, 0.f, 0.f, 0.f};
        if (n0 + nc < N) v = *(const f32x4*)(W + (size_t)(k0 + k) * N + n0 + nc);
        tile[k][nc + 0] = v[0];
        tile[k][nc + 1] = v[1];
        tile[k][nc + 2] = v[2];
        tile[k][nc + 3] = v[3];
    }
    __syncthreads();
    const int nr = tid >> 2;          // 0..63
    const int kc = (tid & 3) * 16;    // 0..48
    ushort8v h0, h1, l0, l1;
#pragma unroll
    for (int j = 0; j < 8; ++j) {
        unsigned short hh, ll;
        split_f32(tile[kc + j][nr], hh, ll);
        h0[j] = hh; l0[j] = ll;
        split_f32(tile[kc + 8 + j][nr], hh, ll);
        h1[j] = hh; l1[j] = ll;
    }
    const size_t o = (size_t)(n0 + nr) * K + k0 + kc;
    *(ushort8v*)(WhT + o)     = h0;
    *(ushort8v*)(WhT + o + 8) = h1;
    *(ushort8v*)(WlT + o)     = l0;
    *(ushort8v*)(WlT + o + 8) = l1;
}

// ---------------------------------------------------------------------------
// Split-bf16 GEMM: C = A @ B (K-slice per blockIdx.z)
//   A_F32: A fp32, converted hi/lo during staging; else A given as planes.
//   EPI=0: +bias, relu, write bf16 hi/lo planes (stride ldC)
//   EPI=1: raw fp32 partial to Cf + z*M*ldC (N padded to ldC, no guard)
// ---------------------------------------------------------------------------
template<bool A_F32, int EPI>
__global__ __launch_bounds__(256, 2)
void gemm3split(const float* __restrict__ A32,
                const unsigned short* __restrict__ Ah,
                const unsigned short* __restrict__ Al,
                const unsigned short* __restrict__ BhT,
                const unsigned short* __restrict__ BlT,
                const float* __restrict__ bias,
                unsigned short* __restrict__ Ch,
                unsigned short* __restrict__ Cl,
                float* __restrict__ Cf,
                int K, int ktiles, int ldC) {
    const int tid  = threadIdx.x;
    const int lane = tid & 63;
    const int wave = tid >> 6;
    const int kgrp = lane >> 4;
    const int m0 = blockIdx.x * BM;
    const int n0 = blockIdx.y * BN;
    const int kt_base = blockIdx.z * ktiles;
    const int wm = (wave >> 1) * 64;
    const int wn = (wave & 1) * 64;

    __shared__ __align__(16) unsigned short sAh[BM * BK];
    __shared__ __align__(16) unsigned short sAl[BM * BK];
    __shared__ __align__(16) unsigned short sBh[BN * BK];
    __shared__ __align__(16) unsigned short sBl[BN * BK];

    f32x4 acc[4][4];
#pragma unroll
    for (int m = 0; m < 4; ++m)
#pragma unroll
        for (int n = 0; n < 4; ++n) acc[m][n] = (f32x4){0.f, 0.f, 0.f, 0.f};

    const int arow   = tid >> 4;   // A_F32 staging: 16 rows x 16 chunks(4 floats)
    const int acol4  = tid & 15;
    const int brow   = tid >> 3;   // bf16 staging: 32 rows x 8 chunks(8 bf16)
    const int bchunk = tid & 7;

    f32x4  aF[8];
    uint4v aH[4], aL[4];
    uint4v bH[4], bL[4];

    auto load_tile = [&](int kt) {
        const int k0 = (kt_base + kt) * BK;
        if constexpr (A_F32) {
#pragma unroll
            for (int i = 0; i < 8; ++i)
                aF[i] = *(const f32x4*)(A32 + (size_t)(m0 + arow + 16 * i) * K + k0 + acol4 * 4);
        } else {
#pragma unroll
            for (int i = 0; i < 4; ++i) {
                const size_t off = (size_t)(m0 + brow + 32 * i) * K + k0 + bchunk * 8;
                aH[i] = *(const uint4v*)(Ah + off);
                aL[i] = *(const uint4v*)(Al + off);
            }
        }
#pragma unroll
        for (int i = 0; i < 4; ++i) {
            const size_t off = (size_t)(n0 + brow + 32 * i) * K + k0 + bchunk * 8;
            bH[i] = *(const uint4v*)(BhT + off);
            bL[i] = *(const uint4v*)(BlT + off);
        }
    };

    auto stage_to_lds = [&]() {
        if constexpr (A_F32) {
#pragma unroll
            for (int i = 0; i < 8; ++i) {
                const int r = arow + 16 * i;
                ushort4v h, l;
#pragma unroll
                for (int j = 0; j < 4; ++j) {
                    unsigned short hh, ll;
                    split_f32(aF[i][j], hh, ll);
                    h[j] = hh; l[j] = ll;
                }
                const int ck  = acol4 >> 1;
                const int sub = (acol4 & 1) * 4;
                const int off = r * BK + ((ck ^ (r & 7)) << 3) + sub;
                *(ushort4v*)(sAh + off) = h;
                *(ushort4v*)(sAl + off) = l;
            }
        } else {
#pragma unroll
            for (int i = 0; i < 4; ++i) {
                const int r   = brow + 32 * i;
                const int off = r * BK + ((bchunk ^ (r & 7)) << 3);
                *(uint4v*)(sAh + off) = aH[i];
                *(uint4v*)(sAl + off) = aL[i];
            }
        }
#pragma unroll
        for (int i = 0; i < 4; ++i) {
            const int r   = brow + 32 * i;
            const int off = r * BK + ((bchunk ^ (r & 7)) << 3);
            *(uint4v*)(sBh + off) = bH[i];
            *(uint4v*)(sBl + off) = bL[i];
        }
    };

    load_tile(0);

    for (int kt = 0; kt < ktiles; ++kt) {
        __syncthreads();                 // prev compute done
        stage_to_lds();
        __syncthreads();                 // LDS ready
        if (kt + 1 < ktiles) load_tile(kt + 1);  // in flight across compute
#pragma unroll
        for (int kk = 0; kk < BK / 32; ++kk) {
            const int ck = kk * 4 + kgrp;
            short8 fah[4], fal[4];
#pragma unroll
            for (int m = 0; m < 4; ++m) {
                const int r   = wm + m * 16 + (lane & 15);
                const int off = r * BK + ((ck ^ (r & 7)) << 3);
                fah[m] = *(const short8*)(sAh + off);
                fal[m] = *(const short8*)(sAl + off);
            }
#pragma unroll
            for (int n = 0; n < 4; ++n) {
                const int r   = wn + n * 16 + (lane & 15);
                const int off = r * BK + ((ck ^ (r & 7)) << 3);
                const short8 fbh = *(const short8*)(sBh + off);
                const short8 fbl = *(const short8*)(sBl + off);
#pragma unroll
                for (int m = 0; m < 4; ++m) {
                    acc[m][n] = __builtin_amdgcn_mfma_f32_16x16x32_bf16(fah[m], fbh, acc[m][n], 0, 0, 0);
                    acc[m][n] = __builtin_amdgcn_mfma_f32_16x16x32_bf16(fah[m], fbl, acc[m][n], 0, 0, 0);
                    acc[m][n] = __builtin_amdgcn_mfma_f32_16x16x32_bf16(fal[m], fbh, acc[m][n], 0, 0, 0);
                }
            }
        }
    }

    // Epilogue. C/D layout (verified): col = lane&15, row = (lane>>4)*4 + reg.
    const int col  = lane & 15;
    const int row4 = (lane >> 4) * 4;
#pragma unroll
    for (int n = 0; n < 4; ++n) {
        const int gn = n0 + wn + n * 16 + col;
        if constexpr (EPI == 0) {
            const float bv = bias[gn];
#pragma unroll
            for (int m = 0; m < 4; ++m) {
                const int gmb = m0 + wm + m * 16 + row4;
#pragma unroll
                for (int j = 0; j < 4; ++j) {
                    float v = acc[m][n][j] + bv;
                    v = fmaxf(v, 0.0f);
                    unsigned short hh, ll;
                    split_f32(v, hh, ll);
                    const size_t o = (size_t)(gmb + j) * ldC + gn;
                    Ch[o] = hh;
                    Cl[o] = ll;
                }
            }
        } else {
            float* Cp = Cf + (size_t)blockIdx.z * (size_t)gridDim.x * BM * ldC;
#pragma unroll
            for (int m = 0; m < 4; ++m) {
                const int gmb = m0 + wm + m * 16 + row4;
#pragma unroll
                for (int j = 0; j < 4; ++j) {
                    Cp[(size_t)(gmb + j) * ldC + gn] = acc[m][n][j];
                }
            }
        }
    }
}

// ---------------------------------------------------------------------------
// reduce: sum nplanes fp32 partials + bias -> relu -> split planes.
// One thread = 4 consecutive elements. ldmask = ldC-1 (power of 2).
// ---------------------------------------------------------------------------
__global__ __launch_bounds__(256) void reduce_relu_split(
        const float* __restrict__ P, size_t planeStride, int nplanes,
        const float* __restrict__ bias, int ldmask,
        unsigned short* __restrict__ Ch, unsigned short* __restrict__ Cl) {
    const size_t base = ((size_t)blockIdx.x * 256 + threadIdx.x) * 4;
    f32x4 s = *(const f32x4*)(P + base);
    for (int z = 1; z < nplanes; ++z)
        s += *(const f32x4*)(P + (size_t)z * planeStride + base);
    const int colb = (int)(base & (size_t)ldmask);
    const f32x4 b = *(const f32x4*)(bias + colb);
    ushort4v h, l;
#pragma unroll
    for (int j = 0; j < 4; ++j) {
        float v = fmaxf(s[j] + b[j], 0.0f);
        unsigned short hh, ll;
        split_f32(v, hh, ll);
        h[j] = hh; l[j] = ll;
    }
    *(ushort4v*)(Ch + base) = h;
    *(ushort4v*)(Cl + base) = l;
}

// ---------------------------------------------------------------------------
// GEMM3 finish: sum 4 partials [4][4096][384] + bias, crop N 384->324.
// grid = (3, 4096), block = 128.
// ---------------------------------------------------------------------------
__global__ __launch_bounds__(128) void reduce_bias_out(
        const float* __restrict__ P, const float* __restrict__ bias,
        float* __restrict__ out) {
    const int col = blockIdx.x * 128 + threadIdx.x;   // 0..383
    const int row = blockIdx.y;
    if (col >= 324) return;
    float s = bias[col];
#pragma unroll
    for (int z = 0; z < 4; ++z)
        s += P[((size_t)z * 4096 + row) * 384 + col];
    out[(size_t)row * 324 + col] = s;
}

// ---------------------------------------------------------------------------
// Workspace layout (bytes). Total = 90,701,824 (same as R1, known to fit).
// Overlays: C1 planes alias W1h region (dead after GEMM1);
//           C2 planes alias W1l region; GEMM3 partials alias P region.
// ---------------------------------------------------------------------------
static constexpr size_t SZ_W1P  = (size_t)1024 * 12544 * 2;   // 25,690,112
static constexpr size_t SZ_W2P  = (size_t)1024 * 1024  * 2;   //  2,097,152
static constexpr size_t SZ_W3P  = (size_t)384  * 1024  * 2;   //    786,432
static constexpr size_t SZ_P    = (size_t)2 * 4096 * 1024 * 4;// 33,554,432
static constexpr size_t SZ_CP   = (size_t)4096 * 1024 * 2;    //  8,388,608
static constexpr size_t OFF_W1H = 0;
static constexpr size_t OFF_W1L = OFF_W1H + SZ_W1P;
static constexpr size_t OFF_W2H = OFF_W1L + SZ_W1P;
static constexpr size_t OFF_W2L = OFF_W2H + SZ_W2P;
static constexpr size_t OFF_W3H = OFF_W2L + SZ_W2P;
static constexpr size_t OFF_W3L = OFF_W3H + SZ_W3P;
static constexpr size_t OFF_P   = OFF_W3L + SZ_W3P;
static constexpr size_t WS_NEED = OFF_P + SZ_P;               // 90,701,824
static constexpr size_t OFF_C1H = OFF_W1H;                    // alias W1h
static constexpr size_t OFF_C1L = OFF_W1H + SZ_CP;
static constexpr size_t OFF_C2H = OFF_W1L;                    // alias W1l
static constexpr size_t OFF_C2L = OFF_W1L + SZ_CP;

extern "C" void kernel_launch(void* const* d_in, const int* in_sizes, int n_in,
                              void* d_out, int out_size, void* d_ws, size_t ws_size,
                              hipStream_t stream) {
    const float* features = (const float*)d_in[0];
    // d_in[1] = batch_indices: mathematically dead (permutation cancels).
    const float* w1 = (const float*)d_in[2];
    const float* b1 = (const float*)d_in[3];
    const float* w2 = (const float*)d_in[4];
    const float* b2 = (const float*)d_in[5];
    const float* w3 = (const float*)d_in[6];
    const float* b3 = (const float*)d_in[7];
    float* out = (float*)d_out;

    if (ws_size < WS_NEED) return;   // visible failure rather than corruption

    char* ws = (char*)d_ws;
    unsigned short* W1h = (unsigned short*)(ws + OFF_W1H);
    unsigned short* W1l = (unsigned short*)(ws + OFF_W1L);
    unsigned short* W2h = (unsigned short*)(ws + OFF_W2H);
    unsigned short* W2l = (unsigned short*)(ws + OFF_W2L);
    unsigned short* W3h = (unsigned short*)(ws + OFF_W3H);
    unsigned short* W3l = (unsigned short*)(ws + OFF_W3L);
    unsigned short* C1h = (unsigned short*)(ws + OFF_C1H);
    unsigned short* C1l = (unsigned short*)(ws + OFF_C1L);
    unsigned short* C2h = (unsigned short*)(ws + OFF_C2H);
    unsigned short* C2l = (unsigned short*)(ws + OFF_C2L);
    float*          P   = (float*)(ws + OFF_P);

    // Weight converts (every launch — same work per call, graph-safe).
    convert_w_t<<<dim3(1024 / 64, 12544 / 64), 256, 0, stream>>>(w1, W1h, W1l, 12544, 1024);
    convert_w_t<<<dim3(1024 / 64, 1024  / 64), 256, 0, stream>>>(w2, W2h, W2l, 1024, 1024);
    convert_w_t<<<dim3(384  / 64, 1024  / 64), 256, 0, stream>>>(w3, W3h, W3l, 1024, 324);

    // L1: [4096,12544]@[12544,1024], split-K=2 -> fp32 partials P[2][4096][1024]
    gemm3split<true, 1><<<dim3(4096 / BM, 1024 / BN, 2), 256, 0, stream>>>(
        features, nullptr, nullptr, W1h, W1l, nullptr, nullptr, nullptr, P,
        12544, 98, 1024);
    // reduce + b1 + relu -> C1 planes
    reduce_relu_split<<<4096, 256, 0, stream>>>(
        P, (size_t)4096 * 1024, 2, b1, 1023, C1h, C1l);

    // L2: [4096,1024]@[1024,1024] -> relu -> C2 planes (no split-K)
    gemm3split<false, 0><<<dim3(4096 / BM, 1024 / BN, 1), 256, 0, stream>>>(
        nullptr, C1h, C1l, W2h, W2l, b2, C2h, C2l, nullptr,
        1024, 16, 1024);

    // L3: [4096,1024]@[1024,384pad], split-K=4 -> fp32 partials P[4][4096][384]
    gemm3split<false, 1><<<dim3(4096 / BM, 384 / BN, 4), 256, 0, stream>>>(
        nullptr, C2h, C2l, W3h, W3l, nullptr, nullptr, nullptr, P,
        1024, 4, 384);
    // reduce + b3, crop 384 -> 324
    reduce_bias_out<<<dim3(3, 4096), 128, 0, stream>>>(P, b3, out);
}